// Round 6
// baseline (653.372 us; speedup 1.0000x reference)
//
#include <hip/hip_runtime.h>
#include <hip/hip_bf16.h>
#include <math.h>

#define IH 48
#define IW 48
#define LTOT 2304      // 48*48
#define CS 128
#define HS 96
#define KRED 1152      // 3*3*128
#define CRED 2048      // 4*4*128

typedef unsigned short u16;
typedef __attribute__((ext_vector_type(8))) short short8;
typedef __attribute__((ext_vector_type(8))) unsigned short ushort8;
typedef __attribute__((ext_vector_type(4))) float floatx4;

#define NS    ((size_t)LTOT*LTOT)     // 5,308,416
#define PLANE ((size_t)LTOT*KRED)     // 2,654,208
#define NRT   ((size_t)CRED*LTOT)     // 4,718,592

// ---- region layout (bytes), per batch slice ----
#define OFF_APL  ((size_t)0)           // 2 bf16 planes (alias: attb)
#define OFF_BPL  ((size_t)10616832)    // 2 bf16 planes (alias: Rt)
#define OFF_S    ((size_t)21233664)    // NS fp32 (raw scores)
#define OFF_S2   ((size_t)42467328)    // Cc (gemm2 out, 18.9MB)
#define OFF_SM   ((size_t)63700992)    // ninv + mmv
#define REGION   ((size_t)63719424)

__device__ __forceinline__ u16 f2bf(float v) {
    __hip_bfloat16 h = __float2bfloat16(v);
    return *reinterpret_cast<u16*>(&h);
}
__device__ __forceinline__ float bf2f(u16 b) {
    __hip_bfloat16 h = *reinterpret_cast<__hip_bfloat16*>(&b);
    return __bfloat162float(h);
}
__device__ __forceinline__ void split2(float v, u16& a, u16& b) {
    a = f2bf(v);
    b = f2bf(v - bf2f(a));
}

// ---------------- norm of W rows (gather-reduce) ----------------
__global__ __launch_bounds__(256) void k_wnorm(const float* __restrict__ b,
                                               float* __restrict__ ninvg,
                                               int b0, size_t zsF) {
    int bi = b0 + blockIdx.z;
    float* ninv = ninvg + (size_t)blockIdx.z * zsF;
    int l = blockIdx.x, t = threadIdx.x;
    __shared__ float red[256];
    float ss = 0.f;
    for (int G = t; G < KRED; G += 256) {
        int F = l * KRED + G;
        int p2 = F / LTOT, s = F - p2 * LTOT;
        int i = p2 / 384, j = (p2 / 128) % 3, c = p2 & 127;
        int u = s / IW + i - 1, v = s % IW + j - 1;
        if (u >= 0 && u < IH && v >= 0 && v < IW) {
            float w = b[(((size_t)bi * CS + c) * HS + 2 * u) * HS + 2 * v];
            ss += w * w;
        }
    }
    red[t] = ss; __syncthreads();
    for (int o = 128; o > 0; o >>= 1) { if (t < o) red[t] += red[t + o]; __syncthreads(); }
    if (t == 0) ninv[l] = 1.0f / fmaxf(sqrtf(red[0] + 1e-8f), 1e-4f);
}

// ---------------- merged gather: W (normalized, split) and Xp (split) ----------------
__global__ __launch_bounds__(256) void k_gather_ab(const float* __restrict__ b,
                                                   const float* __restrict__ f,
                                                   u16* __restrict__ Ag,
                                                   u16* __restrict__ Bg,
                                                   const float* __restrict__ ninvg,
                                                   int b0, size_t zsU, size_t zsF) {
    const unsigned half = (unsigned)(PLANE / 256);
    int bi = b0 + blockIdx.z;
    if (blockIdx.x < half) {
        // W side
        u16* A = Ag + (size_t)blockIdx.z * zsU;
        const float* ninv = ninvg + (size_t)blockIdx.z * zsF;
        int idx = blockIdx.x * 256 + threadIdx.x;
        int p2 = idx / LTOT, s = idx - p2 * LTOT;
        int i = p2 / 384, j = (p2 / 128) % 3, c = p2 & 127;
        int u = s / IW + i - 1, v = s % IW + j - 1;
        float val = 0.f;
        if (u >= 0 && u < IH && v >= 0 && v < IW)
            val = b[(((size_t)bi * CS + c) * HS + 2 * u) * HS + 2 * v];
        val *= ninv[idx / KRED];
        u16 h1, h2; split2(val, h1, h2);
        A[idx] = h1; A[PLANE + idx] = h2;
    } else {
        // Xp side
        u16* B = Bg + (size_t)blockIdx.z * zsU;
        int idx = (blockIdx.x - half) * 256 + threadIdx.x;
        int p = idx / KRED, G = idx - p * KRED;
        int y = p / IW, x = p % IW;
        int k1 = G / 384, k2 = (G / 128) % 3, c = G & 127;
        int u = y + k1 - 1, v = x + k2 - 1;
        float val = 0.f;
        if (u >= 0 && u < IH && v >= 0 && v < IW)
            val = f[(((size_t)bi * CS + c) * HS + 2 * u) * HS + 2 * v];
        u16 h1, h2; split2(val, h1, h2);
        B[idx] = h1; B[PLANE + idx] = h2;
    }
}

// ---------------- mask vector ----------------
__global__ __launch_bounds__(256) void k_mm(const float* __restrict__ mask,
                                            float* __restrict__ mmvg, int b0, size_t zsF) {
    int bi = b0 + blockIdx.z;
    float* out = mmvg + (size_t)blockIdx.z * zsF;
    int q = blockIdx.x * 256 + threadIdx.x;
    if (q >= LTOT) return;
    float ssum = 0.f;
    for (int t = 0; t < 9; t++) {
        int F = q * 9 + t;
        int pm = F / LTOT, s = F % LTOT;
        int i = pm / 3, j = pm % 3;
        int u = s / IW + i - 1, v = s % IW + j - 1;
        float val = 0.f;
        if (u >= 0 && u < IH && v >= 0 && v < IW)
            val = mask[((size_t)bi * HS + 2 * u) * HS + 2 * v];
        ssum += 1.0f - val;
    }
    out[q] = (ssum / 9.0f < 0.85f) ? 1.0f : 0.0f;
}

// ---------------- gather raw patches, pre-transposed: Rt[n][k] ----------------
__global__ __launch_bounds__(256) void k_gather_rt(const float* __restrict__ b,
                                                   u16* __restrict__ Rtg,
                                                   int b0, size_t zsU) {
    int bi = b0 + blockIdx.z;
    u16* Rt = Rtg + (size_t)blockIdx.z * zsU;
    size_t idx = (size_t)blockIdx.x * 256 + threadIdx.x;
    if (idx >= NRT) return;
    int n = (int)(idx / LTOT), k = (int)(idx - (size_t)n * LTOT);
    size_t F = (size_t)k * CRED + n;
    int pr = (int)(F / LTOT);
    int s = (int)(F - (size_t)pr * LTOT);
    int i = pr / 512, j = (pr / 128) & 3, c = pr & 127;
    int Y0 = 2 * (s / IW) + i - 1, X0 = 2 * (s % IW) + j - 1;
    float val = 0.f;
    if (Y0 >= 0 && Y0 < HS && X0 >= 0 && X0 < HS)
        val = b[(((size_t)bi * CS + c) * HS + Y0) * HS + X0];
    Rt[idx] = f2bf(val);
}

// ---------------- MFMA GEMM (NT): C[m,n] = sum_k A[m,k]*B[n,k] ----------------
// 128x128 tile, BK=64, 4 waves (2x2), XOR-8 LDS swizzle (0 conflicts measured),
// T14 2-stage ping-pong register prefetch: GLOAD(next) issued BEFORE COMPUTE(cur),
// so the vmcnt(0) emitted by the following __syncthreads lands AFTER the MFMA block
// (load latency hidden under compute). Bijective XCD swizzle over the full grid.
// NP=2: 3-product split-2 (lo*hi + hi*lo + hi*hi, small-first). NP=1: plain bf16.

#define GLOAD(sta, stb, kt)  do { _Pragma("unroll") \
    for (int e = 0; e < NP * 4; ++e) { \
        int g = e * 256 + tid; int p = g >> 10; int gg = g & 1023; \
        int row = gg >> 3, slot = gg & 7; \
        sta[e] = *(const ushort8*)(A + (size_t)p * planeStride + (size_t)(bm + row) * K + (kt) + slot * 8); \
        stb[e] = *(const ushort8*)(B + (size_t)p * planeStride + (size_t)(bn + row) * K + (kt) + slot * 8); \
    } } while (0)

#define LWRITE(sta, stb) do { _Pragma("unroll") \
    for (int e = 0; e < NP * 4; ++e) { \
        int g = e * 256 + tid; int p = g >> 10; int gg = g & 1023; \
        int row = gg >> 3, slot = gg & 7; \
        int dst = p * 8192 + row * 64 + ((slot ^ (row & 7)) << 3); \
        *(ushort8*)&As[dst] = sta[e]; *(ushort8*)&Bs[dst] = stb[e]; \
    } } while (0)

#define KCOMPUTE() do { _Pragma("unroll") \
    for (int ks = 0; ks < 2; ++ks) { \
        short8 af[NP][4]; \
        _Pragma("unroll") \
        for (int p = 0; p < NP; ++p) \
            _Pragma("unroll") \
            for (int mi = 0; mi < 4; ++mi) { \
                int row = wr + mi * 16 + lrow; \
                af[p][mi] = *(const short8*)&As[p * 8192 + row * 64 + ((((ks << 2) | lq) ^ (row & 7)) << 3)]; \
            } \
        _Pragma("unroll") \
        for (int ni = 0; ni < 4; ++ni) { \
            short8 bfr[NP]; \
            int rowb = wc + ni * 16 + lrow; \
            int bslot = ((((ks << 2) | lq) ^ (rowb & 7)) << 3); \
            _Pragma("unroll") \
            for (int p = 0; p < NP; ++p) \
                bfr[p] = *(const short8*)&Bs[p * 8192 + rowb * 64 + bslot]; \
            _Pragma("unroll") \
            for (int mi = 0; mi < 4; ++mi) { \
                if constexpr (NP == 1) { \
                    acc[mi][ni] = __builtin_amdgcn_mfma_f32_16x16x32_bf16(af[0][mi], bfr[0], acc[mi][ni], 0, 0, 0); \
                } else { \
                    acc[mi][ni] = __builtin_amdgcn_mfma_f32_16x16x32_bf16(af[1][mi], bfr[0], acc[mi][ni], 0, 0, 0); \
                    acc[mi][ni] = __builtin_amdgcn_mfma_f32_16x16x32_bf16(af[0][mi], bfr[1], acc[mi][ni], 0, 0, 0); \
                    acc[mi][ni] = __builtin_amdgcn_mfma_f32_16x16x32_bf16(af[0][mi], bfr[0], acc[mi][ni], 0, 0, 0); \
                } \
            } \
        } \
    } } while (0)

template <int NP>
__global__ __launch_bounds__(256) void k_gemm_mfma(const u16* __restrict__ Ag,
                                                   const u16* __restrict__ Bg,
                                                   float* __restrict__ Cg,
                                                   size_t zsA, size_t zsB, size_t zsC,
                                                   size_t planeStride,
                                                   int M, int N, int K) {
    __shared__ u16 lds[NP * 8192 * 2];
    u16* As = lds;
    u16* Bs = lds + NP * 8192;
    const int tid = threadIdx.x;
    const int lane = tid & 63;
    const int wave = tid >> 6;
    const int wr = (wave >> 1) * 64, wc = (wave & 1) * 64;
    const int lrow = lane & 15, lq = lane >> 4;

    // bijective XCD swizzle over the whole 3D grid (m204 formula)
    unsigned gx = gridDim.x, gy = gridDim.y;
    unsigned nwg = gx * gy * gridDim.z;
    unsigned wg = (blockIdx.z * gy + blockIdx.y) * gx + blockIdx.x;
    {
        unsigned q = nwg >> 3, r = nwg & 7, xcd = wg & 7, lid = wg >> 3;
        wg = (xcd < r ? xcd * (q + 1) : r * (q + 1) + (xcd - r) * q) + lid;
    }
    unsigned z = wg / (gx * gy);
    unsigned rem2 = wg - z * gx * gy;
    const int bm = (int)(rem2 / gx) * 128, bn = (int)(rem2 % gx) * 128;

    const u16* A = Ag + (size_t)z * zsA;
    const u16* B = Bg + (size_t)z * zsB;
    float* C = Cg + (size_t)z * zsC;

    floatx4 acc[4][4];
#pragma unroll
    for (int i = 0; i < 4; i++)
#pragma unroll
        for (int j = 0; j < 4; j++) acc[i][j] = (floatx4){0.f, 0.f, 0.f, 0.f};

    ushort8 sA0[NP * 4], sB0[NP * 4], sA1[NP * 4], sB1[NP * 4];
    const int ktiles = K >> 6;   // always even for our shapes (18 / 36)
    GLOAD(sA0, sB0, 0);
    for (int tt = 0; tt < ktiles; tt += 2) {
        __syncthreads();                 // prev compute done reading LDS; waits sA0 loads
        LWRITE(sA0, sB0);                // sA0 dies
        __syncthreads();
        GLOAD(sA1, sB1, (tt + 1) << 6);  // issue next-tile loads (overlap MFMA below)
        KCOMPUTE();
        __syncthreads();                 // waits sA1 loads (landed during compute)
        LWRITE(sA1, sB1);                // sA1 dies
        __syncthreads();
        if (tt + 2 < ktiles) GLOAD(sA0, sB0, (tt + 2) << 6);
        KCOMPUTE();
    }

    const int r0 = bm + wr + (lane >> 4) * 4;
    const int c0 = bn + wc + (lane & 15);
#pragma unroll
    for (int mi = 0; mi < 4; ++mi)
#pragma unroll
        for (int ni = 0; ni < 4; ++ni)
#pragma unroll
            for (int j = 0; j < 4; ++j)
                C[(size_t)(r0 + mi * 16 + j) * N + (c0 + ni * 16)] = acc[mi][ni][j];
}

#undef GLOAD
#undef LWRITE
#undef KCOMPUTE

// ---------------- fused fuse1+fuse2+softmax+argmax ----------------
__device__ __forceinline__ int permi(int a) { return (a % 48) * 48 + a / 48; }

__device__ __forceinline__ float f1_at(const float* __restrict__ S, int a, int b) {
    float s = S[(size_t)a * LTOT + b];
    if (a >= 1 && b >= 1) s += S[(size_t)(a - 1) * LTOT + (b - 1)];
    if (a < LTOT - 1 && b < LTOT - 1) s += S[(size_t)(a + 1) * LTOT + (b + 1)];
    return s;
}

__global__ __launch_bounds__(256) void k_fusesoftmax(const float* __restrict__ Sg,
                                                     const float* __restrict__ mmg,
                                                     u16* __restrict__ attbg,
                                                     float* __restrict__ offout,
                                                     int b0, size_t zsF, size_t zsU) {
    int bi = b0 + blockIdx.z;
    const float* S = Sg + (size_t)blockIdx.z * zsF;
    const float* mm = mmg + (size_t)blockIdx.z * zsF;
    u16* attb = attbg + (size_t)blockIdx.z * zsU;
    int l = blockIdx.x, t = threadIdx.x;
    __shared__ float red[256];
    __shared__ int redi[256];
    u16* arow = attb + (size_t)l * LTOT;

    const int At = permi(l);
    const int rm = (At >= 1) ? permi(At - 1) : -1;          // wave-uniform rows
    const int rp = (At < LTOT - 1) ? permi(At + 1) : -1;

    float v[9], m9[9];
#pragma unroll
    for (int i = 0; i < 9; ++i) {
        int p = t + 256 * i;
        float d = f1_at(S, l, p);
        int Bt = permi(p);
        if (rm >= 0 && Bt >= 1)        d += f1_at(S, rm, permi(Bt - 1));
        if (rp >= 0 && Bt < LTOT - 1)  d += f1_at(S, rp, permi(Bt + 1));
        m9[i] = mm[p];
        v[i] = d * m9[i] * 10.0f;
    }
    float mx = -1e30f;
#pragma unroll
    for (int i = 0; i < 9; ++i) mx = fmaxf(mx, v[i]);
    red[t] = mx; __syncthreads();
    for (int o = 128; o > 0; o >>= 1) { if (t < o) red[t] = fmaxf(red[t], red[t + o]); __syncthreads(); }
    mx = red[0]; __syncthreads();
    float sm = 0.f;
#pragma unroll
    for (int i = 0; i < 9; ++i) sm += expf(v[i] - mx);
    red[t] = sm; __syncthreads();
    for (int o = 128; o > 0; o >>= 1) { if (t < o) red[t] += red[t + o]; __syncthreads(); }
    float Z = red[0]; __syncthreads();
    float bv = -1.0f; int bidx2 = 0;
#pragma unroll
    for (int i = 0; i < 9; ++i) {
        int p = t + 256 * i;
        float e = expf(v[i] - mx);
        float a = (e / Z) * m9[i];
        arow[p] = f2bf(a);
        if (a > bv) { bv = a; bidx2 = p; }
    }
    red[t] = bv; redi[t] = bidx2; __syncthreads();
    for (int o = 128; o > 0; o >>= 1) {
        if (t < o) {
            if (red[t + o] > red[t] || (red[t + o] == red[t] && redi[t + o] < redi[t])) {
                red[t] = red[t + o]; redi[t] = redi[t + o];
            }
        }
        __syncthreads();
    }
    if (t == 0) {
        int off = redi[0];
        int ly = l / IW, lx = l % IW;
        offout[((size_t)bi * 2 + 0) * LTOT + l] = (float)(off / 96 - ly);
        offout[((size_t)bi * 2 + 1) * LTOT + l] = (float)(off % 96 - lx);
    }
}

// ---------------- transposed-conv reduction ----------------
__global__ __launch_bounds__(256) void k_output(const float* __restrict__ Cg,
                                                float* __restrict__ yout,
                                                int b0, size_t zsF) {
    int bi = b0 + blockIdx.z;
    const float* C = Cg + (size_t)blockIdx.z * zsF;
    int idx = blockIdx.x * 256 + threadIdx.x;
    if (idx >= CS * HS * HS) return;
    int c = idx / (HS * HS), rem = idx % (HS * HS);
    int Y = rem / HS, X = rem % HS;
    float s = 0.f;
    int pu = (Y + 1) & 1, pv = (X + 1) & 1;
    for (int a = 0; a < 2; a++) {
        int u = pu + 2 * a;
        int ly2 = Y + 1 - u;
        if (ly2 < 0) continue;
        int ly = ly2 >> 1;
        if (ly >= IH) continue;
        for (int bb = 0; bb < 2; bb++) {
            int v = pv + 2 * bb;
            int lx2 = X + 1 - v;
            if (lx2 < 0) continue;
            int lx = lx2 >> 1;
            if (lx >= IW) continue;
            s += C[(size_t)(ly * IW + lx) * CRED + u * 512 + v * 128 + c];
        }
    }
    yout[(size_t)bi * CS * HS * HS + idx] = s * 0.25f;
}

// ---------------- launch ----------------
extern "C" void kernel_launch(void* const* d_in, const int* in_sizes, int n_in,
                              void* d_out, int out_size, void* d_ws, size_t ws_size,
                              hipStream_t stream) {
    const float* f = (const float*)d_in[0];
    const float* b = (const float*)d_in[1];
    const float* mask = (const float*)d_in[2];
    float* yout = (float*)d_out;
    float* offout = yout + (size_t)4 * CS * HS * HS;

    int ZB, nloop;
    if (ws_size >= 4 * REGION)      { ZB = 4; nloop = 1; }
    else if (ws_size >= 2 * REGION) { ZB = 2; nloop = 2; }
    else                            { ZB = 1; nloop = 4; }

    char* base = (char*)d_ws;
    u16*   Apl  = (u16*)(base + OFF_APL);
    u16*   Bpl  = (u16*)(base + OFF_BPL);
    float* S    = (float*)(base + OFF_S);
    float* Cc   = (float*)(base + OFF_S2);
    float* ninv = (float*)(base + OFF_SM);
    float* mmv  = ninv + LTOT;
    u16*   attb = Apl;   // alias (A planes dead after gemm1)
    u16*   Rt   = Bpl;   // alias (B planes dead after gemm1)

    const size_t zsU = REGION / 2;   // per-z stride in u16 elements
    const size_t zsF = REGION / 4;   // per-z stride in float elements

    dim3 blk(256, 1, 1);
    const unsigned ghalf = (unsigned)(PLANE / 256);

    for (int it = 0; it < nloop; ++it) {
        int b0 = it * ZB;
        k_wnorm<<<dim3(LTOT, 1, ZB), blk, 0, stream>>>(b, ninv, b0, zsF);
        k_gather_ab<<<dim3(2 * ghalf, 1, ZB), blk, 0, stream>>>(b, f, Apl, Bpl, ninv, b0, zsU, zsF);
        k_mm<<<dim3((LTOT + 255) / 256, 1, ZB), blk, 0, stream>>>(mask, mmv, b0, zsF);
        // GEMM1: S[l,p] = Wn . Xp^T : M=N=2304, K=1152, split-2, 3 products
        k_gemm_mfma<2><<<dim3(LTOT / 128, LTOT / 128, ZB), blk, 0, stream>>>(
            Apl, Bpl, S, zsU, zsU, zsF, PLANE, LTOT, LTOT, KRED);
        // fused fuse1+fuse2+softmax+argmax
        k_fusesoftmax<<<dim3(LTOT, 1, ZB), blk, 0, stream>>>(S, mmv, attb, offout, b0, zsF, zsU);
        k_gather_rt<<<dim3((unsigned)(NRT / 256), 1, ZB), blk, 0, stream>>>(b, Rt, b0, zsU);
        // GEMM2: C[l,G2] = att . Rt^T : M=2304, N=2048, K=2304, plain bf16
        k_gemm_mfma<1><<<dim3(CRED / 128, LTOT / 128, ZB), blk, 0, stream>>>(
            attb, Rt, Cc, zsU, zsU, zsF, PLANE, LTOT, CRED, LTOT);
        k_output<<<dim3((CS * HS * HS) / 256, 1, ZB), blk, 0, stream>>>(Cc, yout, b0, zsF);
    }
}

// Round 7
// 606.492 us; speedup vs baseline: 1.0773x; 1.0773x over previous
//
#include <hip/hip_runtime.h>
#include <hip/hip_bf16.h>
#include <math.h>

#define IH 48
#define IW 48
#define LTOT 2304      // 48*48
#define CS 128
#define HS 96
#define KRED 1152      // 3*3*128
#define CRED 2048      // 4*4*128

typedef unsigned short u16;
typedef __attribute__((ext_vector_type(8))) short short8;
typedef __attribute__((ext_vector_type(8))) unsigned short ushort8;
typedef __attribute__((ext_vector_type(4))) float floatx4;

#define NS    ((size_t)LTOT*LTOT)     // 5,308,416
#define PLANE ((size_t)LTOT*KRED)     // 2,654,208
#define NRT   ((size_t)CRED*LTOT)     // 4,718,592

// ---- region layout (bytes), per batch slice ----
#define OFF_APL  ((size_t)0)           // 2 bf16 planes (alias: attb)
#define OFF_BPL  ((size_t)10616832)    // 2 bf16 planes (alias: Rt)
#define OFF_S    ((size_t)21233664)    // NS fp32 (raw scores)
#define OFF_S2   ((size_t)42467328)    // Cc (gemm2 out, 18.9MB)
#define OFF_SM   ((size_t)63700992)    // ninv + mmv
#define REGION   ((size_t)63719424)

__device__ __forceinline__ u16 f2bf(float v) {
    __hip_bfloat16 h = __float2bfloat16(v);
    return *reinterpret_cast<u16*>(&h);
}
__device__ __forceinline__ float bf2f(u16 b) {
    __hip_bfloat16 h = *reinterpret_cast<__hip_bfloat16*>(&b);
    return __bfloat162float(h);
}
__device__ __forceinline__ void split2(float v, u16& a, u16& b) {
    a = f2bf(v);
    b = f2bf(v - bf2f(a));
}

// ---------------- norm of W rows (gather-reduce) ----------------
__global__ __launch_bounds__(256) void k_wnorm(const float* __restrict__ b,
                                               float* __restrict__ ninvg,
                                               int b0, size_t zsF) {
    int bi = b0 + blockIdx.z;
    float* ninv = ninvg + (size_t)blockIdx.z * zsF;
    int l = blockIdx.x, t = threadIdx.x;
    __shared__ float red[256];
    float ss = 0.f;
    for (int G = t; G < KRED; G += 256) {
        int F = l * KRED + G;
        int p2 = F / LTOT, s = F - p2 * LTOT;
        int i = p2 / 384, j = (p2 / 128) % 3, c = p2 & 127;
        int u = s / IW + i - 1, v = s % IW + j - 1;
        if (u >= 0 && u < IH && v >= 0 && v < IW) {
            float w = b[(((size_t)bi * CS + c) * HS + 2 * u) * HS + 2 * v];
            ss += w * w;
        }
    }
    red[t] = ss; __syncthreads();
    for (int o = 128; o > 0; o >>= 1) { if (t < o) red[t] += red[t + o]; __syncthreads(); }
    if (t == 0) ninv[l] = 1.0f / fmaxf(sqrtf(red[0] + 1e-8f), 1e-4f);
}

// ---------------- merged gather: W (normalized, split) and Xp (split) ----------------
__global__ __launch_bounds__(256) void k_gather_ab(const float* __restrict__ b,
                                                   const float* __restrict__ f,
                                                   u16* __restrict__ Ag,
                                                   u16* __restrict__ Bg,
                                                   const float* __restrict__ ninvg,
                                                   int b0, size_t zsU, size_t zsF) {
    const unsigned half = (unsigned)(PLANE / 256);
    int bi = b0 + blockIdx.z;
    if (blockIdx.x < half) {
        // W side
        u16* A = Ag + (size_t)blockIdx.z * zsU;
        const float* ninv = ninvg + (size_t)blockIdx.z * zsF;
        int idx = blockIdx.x * 256 + threadIdx.x;
        int p2 = idx / LTOT, s = idx - p2 * LTOT;
        int i = p2 / 384, j = (p2 / 128) % 3, c = p2 & 127;
        int u = s / IW + i - 1, v = s % IW + j - 1;
        float val = 0.f;
        if (u >= 0 && u < IH && v >= 0 && v < IW)
            val = b[(((size_t)bi * CS + c) * HS + 2 * u) * HS + 2 * v];
        val *= ninv[idx / KRED];
        u16 h1, h2; split2(val, h1, h2);
        A[idx] = h1; A[PLANE + idx] = h2;
    } else {
        // Xp side
        u16* B = Bg + (size_t)blockIdx.z * zsU;
        int idx = (blockIdx.x - half) * 256 + threadIdx.x;
        int p = idx / KRED, G = idx - p * KRED;
        int y = p / IW, x = p % IW;
        int k1 = G / 384, k2 = (G / 128) % 3, c = G & 127;
        int u = y + k1 - 1, v = x + k2 - 1;
        float val = 0.f;
        if (u >= 0 && u < IH && v >= 0 && v < IW)
            val = f[(((size_t)bi * CS + c) * HS + 2 * u) * HS + 2 * v];
        u16 h1, h2; split2(val, h1, h2);
        B[idx] = h1; B[PLANE + idx] = h2;
    }
}

// ---------------- mask vector ----------------
__global__ __launch_bounds__(256) void k_mm(const float* __restrict__ mask,
                                            float* __restrict__ mmvg, int b0, size_t zsF) {
    int bi = b0 + blockIdx.z;
    float* out = mmvg + (size_t)blockIdx.z * zsF;
    int q = blockIdx.x * 256 + threadIdx.x;
    if (q >= LTOT) return;
    float ssum = 0.f;
    for (int t = 0; t < 9; t++) {
        int F = q * 9 + t;
        int pm = F / LTOT, s = F % LTOT;
        int i = pm / 3, j = pm % 3;
        int u = s / IW + i - 1, v = s % IW + j - 1;
        float val = 0.f;
        if (u >= 0 && u < IH && v >= 0 && v < IW)
            val = mask[((size_t)bi * HS + 2 * u) * HS + 2 * v];
        ssum += 1.0f - val;
    }
    out[q] = (ssum / 9.0f < 0.85f) ? 1.0f : 0.0f;
}

// ---------------- gather raw patches, pre-transposed: Rt[n][k] ----------------
__global__ __launch_bounds__(256) void k_gather_rt(const float* __restrict__ b,
                                                   u16* __restrict__ Rtg,
                                                   int b0, size_t zsU) {
    int bi = b0 + blockIdx.z;
    u16* Rt = Rtg + (size_t)blockIdx.z * zsU;
    size_t idx = (size_t)blockIdx.x * 256 + threadIdx.x;
    if (idx >= NRT) return;
    int n = (int)(idx / LTOT), k = (int)(idx - (size_t)n * LTOT);
    size_t F = (size_t)k * CRED + n;
    int pr = (int)(F / LTOT);
    int s = (int)(F - (size_t)pr * LTOT);
    int i = pr / 512, j = (pr / 128) & 3, c = pr & 127;
    int Y0 = 2 * (s / IW) + i - 1, X0 = 2 * (s % IW) + j - 1;
    float val = 0.f;
    if (Y0 >= 0 && Y0 < HS && X0 >= 0 && X0 < HS)
        val = b[(((size_t)bi * CS + c) * HS + Y0) * HS + X0];
    Rt[idx] = f2bf(val);
}

// ---------------- MFMA GEMM (NT): C[m,n] = sum_k A[m,k]*B[n,k] ----------------
// Round-5 proven structure: 128x128 tile, 4 waves (2x2), XOR LDS swizzle
// (0 bank conflicts measured), reg-staged, 2-barrier loop, bijective XCD swizzle.
// Template BK: per-barrier K-depth. NP=2/BK=64: 96 MFMA/iter (gemm1).
// NP=1/BK=128: 64 MFMA/iter (gemm2) — same LDS (64KB) and staging regs as gemm1.
template <int NP, int BK>
__global__ __launch_bounds__(256) void k_gemm_mfma(const u16* __restrict__ Ag,
                                                   const u16* __restrict__ Bg,
                                                   float* __restrict__ Cg,
                                                   size_t zsA, size_t zsB, size_t zsC,
                                                   size_t planeStride,
                                                   int M, int N, int K) {
    constexpr int SLOTS = BK / 8;        // 16B slots per row
    constexpr int SMASK = SLOTS - 1;
    constexpr int TSZ = 128 * BK;        // u16 per (plane,side) tile
    constexpr int NLD = NP * BK / 16;    // ushort8 loads per side per thread
    __shared__ u16 lds[2 * NP * TSZ];
    u16* As = lds;
    u16* Bs = lds + NP * TSZ;
    const int tid = threadIdx.x;
    const int lane = tid & 63;
    const int wave = tid >> 6;
    const int wr = (wave >> 1) * 64, wc = (wave & 1) * 64;
    const int lrow = lane & 15, lq = lane >> 4;

    // bijective XCD swizzle over the whole 3D grid (m204 formula)
    unsigned gx = gridDim.x, gy = gridDim.y;
    unsigned nwg = gx * gy * gridDim.z;
    unsigned wg = (blockIdx.z * gy + blockIdx.y) * gx + blockIdx.x;
    {
        unsigned q = nwg >> 3, r = nwg & 7, xcd = wg & 7, lid = wg >> 3;
        wg = (xcd < r ? xcd * (q + 1) : r * (q + 1) + (xcd - r) * q) + lid;
    }
    unsigned z = wg / (gx * gy);
    unsigned rem2 = wg - z * gx * gy;
    const int bm = (int)(rem2 / gx) * 128, bn = (int)(rem2 % gx) * 128;

    const u16* A = Ag + (size_t)z * zsA;
    const u16* B = Bg + (size_t)z * zsB;
    float* C = Cg + (size_t)z * zsC;

    floatx4 acc[4][4];
#pragma unroll
    for (int i = 0; i < 4; i++)
#pragma unroll
        for (int j = 0; j < 4; j++) acc[i][j] = (floatx4){0.f, 0.f, 0.f, 0.f};

    for (int kt = 0; kt < K; kt += BK) {
        ushort8 stA[NLD], stB[NLD];
#pragma unroll
        for (int e = 0; e < NLD; ++e) {
            int g = e * 256 + tid;
            int p = g / (128 * SLOTS);
            int gg = g % (128 * SLOTS);
            int row = gg / SLOTS, slot = gg & SMASK;
            stA[e] = *(const ushort8*)(A + (size_t)p * planeStride + (size_t)(bm + row) * K + kt + slot * 8);
            stB[e] = *(const ushort8*)(B + (size_t)p * planeStride + (size_t)(bn + row) * K + kt + slot * 8);
        }
        __syncthreads();   // prior compute finished reading LDS
#pragma unroll
        for (int e = 0; e < NLD; ++e) {
            int g = e * 256 + tid;
            int p = g / (128 * SLOTS);
            int gg = g % (128 * SLOTS);
            int row = gg / SLOTS, slot = gg & SMASK;
            int dst = p * TSZ + row * BK + ((slot ^ (row & SMASK)) << 3);
            *(ushort8*)&As[dst] = stA[e];
            *(ushort8*)&Bs[dst] = stB[e];
        }
        __syncthreads();

#pragma unroll
        for (int ks = 0; ks < BK / 32; ++ks) {
            short8 af[NP][4];
#pragma unroll
            for (int p = 0; p < NP; ++p)
#pragma unroll
                for (int mi = 0; mi < 4; ++mi) {
                    int row = wr + mi * 16 + lrow;
                    af[p][mi] = *(const short8*)&As[p * TSZ + row * BK + ((((ks << 2) | lq) ^ (row & SMASK)) << 3)];
                }
#pragma unroll
            for (int ni = 0; ni < 4; ++ni) {
                short8 bfr[NP];
                int rowb = wc + ni * 16 + lrow;
                int bslot = ((((ks << 2) | lq) ^ (rowb & SMASK)) << 3);
#pragma unroll
                for (int p = 0; p < NP; ++p)
                    bfr[p] = *(const short8*)&Bs[p * TSZ + rowb * BK + bslot];
#pragma unroll
                for (int mi = 0; mi < 4; ++mi) {
                    if constexpr (NP == 1) {
                        acc[mi][ni] = __builtin_amdgcn_mfma_f32_16x16x32_bf16(af[0][mi], bfr[0], acc[mi][ni], 0, 0, 0);
                    } else {
                        // small-first: lo*hi, hi*lo, hi*hi
                        acc[mi][ni] = __builtin_amdgcn_mfma_f32_16x16x32_bf16(af[1][mi], bfr[0], acc[mi][ni], 0, 0, 0);
                        acc[mi][ni] = __builtin_amdgcn_mfma_f32_16x16x32_bf16(af[0][mi], bfr[1], acc[mi][ni], 0, 0, 0);
                        acc[mi][ni] = __builtin_amdgcn_mfma_f32_16x16x32_bf16(af[0][mi], bfr[0], acc[mi][ni], 0, 0, 0);
                    }
                }
            }
        }
    }

    const int r0 = bm + wr + (lane >> 4) * 4;
    const int c0 = bn + wc + (lane & 15);
#pragma unroll
    for (int mi = 0; mi < 4; ++mi)
#pragma unroll
        for (int ni = 0; ni < 4; ++ni)
#pragma unroll
            for (int j = 0; j < 4; ++j)
                C[(size_t)(r0 + mi * 16 + j) * N + (c0 + ni * 16)] = acc[mi][ni][j];
}

// ---------------- fused fuse1+fuse2+softmax+argmax ----------------
__device__ __forceinline__ int permi(int a) { return (a % 48) * 48 + a / 48; }

__device__ __forceinline__ float f1_at(const float* __restrict__ S, int a, int b) {
    float s = S[(size_t)a * LTOT + b];
    if (a >= 1 && b >= 1) s += S[(size_t)(a - 1) * LTOT + (b - 1)];
    if (a < LTOT - 1 && b < LTOT - 1) s += S[(size_t)(a + 1) * LTOT + (b + 1)];
    return s;
}

__global__ __launch_bounds__(256) void k_fusesoftmax(const float* __restrict__ Sg,
                                                     const float* __restrict__ mmg,
                                                     u16* __restrict__ attbg,
                                                     float* __restrict__ offout,
                                                     int b0, size_t zsF, size_t zsU) {
    int bi = b0 + blockIdx.z;
    const float* S = Sg + (size_t)blockIdx.z * zsF;
    const float* mm = mmg + (size_t)blockIdx.z * zsF;
    u16* attb = attbg + (size_t)blockIdx.z * zsU;
    int l = blockIdx.x, t = threadIdx.x;
    __shared__ float red[256];
    __shared__ int redi[256];
    u16* arow = attb + (size_t)l * LTOT;

    const int At = permi(l);
    const int rm = (At >= 1) ? permi(At - 1) : -1;          // wave-uniform rows
    const int rp = (At < LTOT - 1) ? permi(At + 1) : -1;

    float v[9], m9[9];
#pragma unroll
    for (int i = 0; i < 9; ++i) {
        int p = t + 256 * i;
        float d = f1_at(S, l, p);
        int Bt = permi(p);
        if (rm >= 0 && Bt >= 1)        d += f1_at(S, rm, permi(Bt - 1));
        if (rp >= 0 && Bt < LTOT - 1)  d += f1_at(S, rp, permi(Bt + 1));
        m9[i] = mm[p];
        v[i] = d * m9[i] * 10.0f;
    }
    float mx = -1e30f;
#pragma unroll
    for (int i = 0; i < 9; ++i) mx = fmaxf(mx, v[i]);
    red[t] = mx; __syncthreads();
    for (int o = 128; o > 0; o >>= 1) { if (t < o) red[t] = fmaxf(red[t], red[t + o]); __syncthreads(); }
    mx = red[0]; __syncthreads();
    float sm = 0.f;
#pragma unroll
    for (int i = 0; i < 9; ++i) sm += expf(v[i] - mx);
    red[t] = sm; __syncthreads();
    for (int o = 128; o > 0; o >>= 1) { if (t < o) red[t] += red[t + o]; __syncthreads(); }
    float Z = red[0]; __syncthreads();
    float bv = -1.0f; int bidx2 = 0;
#pragma unroll
    for (int i = 0; i < 9; ++i) {
        int p = t + 256 * i;
        float e = expf(v[i] - mx);
        float a = (e / Z) * m9[i];
        arow[p] = f2bf(a);
        if (a > bv) { bv = a; bidx2 = p; }
    }
    red[t] = bv; redi[t] = bidx2; __syncthreads();
    for (int o = 128; o > 0; o >>= 1) {
        if (t < o) {
            if (red[t + o] > red[t] || (red[t + o] == red[t] && redi[t + o] < redi[t])) {
                red[t] = red[t + o]; redi[t] = redi[t + o];
            }
        }
        __syncthreads();
    }
    if (t == 0) {
        int off = redi[0];
        int ly = l / IW, lx = l % IW;
        offout[((size_t)bi * 2 + 0) * LTOT + l] = (float)(off / 96 - ly);
        offout[((size_t)bi * 2 + 1) * LTOT + l] = (float)(off % 96 - lx);
    }
}

// ---------------- transposed-conv reduction ----------------
__global__ __launch_bounds__(256) void k_output(const float* __restrict__ Cg,
                                                float* __restrict__ yout,
                                                int b0, size_t zsF) {
    int bi = b0 + blockIdx.z;
    const float* C = Cg + (size_t)blockIdx.z * zsF;
    int idx = blockIdx.x * 256 + threadIdx.x;
    if (idx >= CS * HS * HS) return;
    int c = idx / (HS * HS), rem = idx % (HS * HS);
    int Y = rem / HS, X = rem % HS;
    float s = 0.f;
    int pu = (Y + 1) & 1, pv = (X + 1) & 1;
    for (int a = 0; a < 2; a++) {
        int u = pu + 2 * a;
        int ly2 = Y + 1 - u;
        if (ly2 < 0) continue;
        int ly = ly2 >> 1;
        if (ly >= IH) continue;
        for (int bb = 0; bb < 2; bb++) {
            int v = pv + 2 * bb;
            int lx2 = X + 1 - v;
            if (lx2 < 0) continue;
            int lx = lx2 >> 1;
            if (lx >= IW) continue;
            s += C[(size_t)(ly * IW + lx) * CRED + u * 512 + v * 128 + c];
        }
    }
    yout[(size_t)bi * CS * HS * HS + idx] = s * 0.25f;
}

// ---------------- launch ----------------
extern "C" void kernel_launch(void* const* d_in, const int* in_sizes, int n_in,
                              void* d_out, int out_size, void* d_ws, size_t ws_size,
                              hipStream_t stream) {
    const float* f = (const float*)d_in[0];
    const float* b = (const float*)d_in[1];
    const float* mask = (const float*)d_in[2];
    float* yout = (float*)d_out;
    float* offout = yout + (size_t)4 * CS * HS * HS;

    int ZB, nloop;
    if (ws_size >= 4 * REGION)      { ZB = 4; nloop = 1; }
    else if (ws_size >= 2 * REGION) { ZB = 2; nloop = 2; }
    else                            { ZB = 1; nloop = 4; }

    char* base = (char*)d_ws;
    u16*   Apl  = (u16*)(base + OFF_APL);
    u16*   Bpl  = (u16*)(base + OFF_BPL);
    float* S    = (float*)(base + OFF_S);
    float* Cc   = (float*)(base + OFF_S2);
    float* ninv = (float*)(base + OFF_SM);
    float* mmv  = ninv + LTOT;
    u16*   attb = Apl;   // alias (A planes dead after gemm1)
    u16*   Rt   = Bpl;   // alias (B planes dead after gemm1)

    const size_t zsU = REGION / 2;   // per-z stride in u16 elements
    const size_t zsF = REGION / 4;   // per-z stride in float elements

    dim3 blk(256, 1, 1);
    const unsigned ghalf = (unsigned)(PLANE / 256);

    for (int it = 0; it < nloop; ++it) {
        int b0 = it * ZB;
        k_wnorm<<<dim3(LTOT, 1, ZB), blk, 0, stream>>>(b, ninv, b0, zsF);
        k_gather_ab<<<dim3(2 * ghalf, 1, ZB), blk, 0, stream>>>(b, f, Apl, Bpl, ninv, b0, zsU, zsF);
        k_mm<<<dim3((LTOT + 255) / 256, 1, ZB), blk, 0, stream>>>(mask, mmv, b0, zsF);
        // GEMM1: S[l,p] = Wn . Xp^T : M=N=2304, K=1152, split-2, 3 products, BK=64
        k_gemm_mfma<2, 64><<<dim3(LTOT / 128, LTOT / 128, ZB), blk, 0, stream>>>(
            Apl, Bpl, S, zsU, zsU, zsF, PLANE, LTOT, LTOT, KRED);
        // fused fuse1+fuse2+softmax+argmax
        k_fusesoftmax<<<dim3(LTOT, 1, ZB), blk, 0, stream>>>(S, mmv, attb, offout, b0, zsF, zsU);
        k_gather_rt<<<dim3((unsigned)(NRT / 256), 1, ZB), blk, 0, stream>>>(b, Rt, b0, zsU);
        // GEMM2: C[l,G2] = att . Rt^T : M=2304, N=2048, K=2304, plain bf16, BK=128
        k_gemm_mfma<1, 128><<<dim3(CRED / 128, LTOT / 128, ZB), blk, 0, stream>>>(
            attb, Rt, Cc, zsU, zsU, zsF, PLANE, LTOT, CRED, LTOT);
        k_output<<<dim3((CS * HS * HS) / 256, 1, ZB), blk, 0, stream>>>(Cc, yout, b0, zsF);
    }
}